// Round 4
// baseline (1919.347 us; speedup 1.0000x reference)
//
#include <hip/hip_runtime.h>
#include <cstddef>

#define B_ 32
#define C_ 32
#define L_ 16384
#define H_ 4
#define DH_ 8
#define NB_ 3
#define DOUT_ 10
#define SEG_ 2048
#define S_ (L_/SEG_)   // 8 segments

// Branch-free gelu via Abramowitz-Stegun 7.1.26 erf approximation (|eps|<=1.5e-7).
__device__ __forceinline__ float gelu_f(float x){
    const float z  = fabsf(x) * 0.70710678118654752440f;
    const float t  = __builtin_amdgcn_rcpf(fmaf(0.3275911f, z, 1.0f));
    const float e  = __expf(-z * z);
    float p = fmaf(t, 1.061405429f, -1.453152027f);
    p = fmaf(t, p, 1.421413741f);
    p = fmaf(t, p, -0.284496736f);
    p = fmaf(t, p, 0.254829592f);
    const float erfz = 1.0f - p * t * e;          // erf(|x|/sqrt(2))
    const float phi  = fmaf(copysignf(erfz, x), 0.5f, 0.5f);
    return x * phi;
}

// ---- stats: per (b, head, seg) partial max / sumexp / kv over a 2048-pos segment ----
__global__ __launch_bounds__(256) void stats_kernel(const float* __restrict__ h,
                                                    float* __restrict__ part){
    const int seg = blockIdx.x;
    const int hd  = blockIdx.y;
    const int b   = blockIdx.z;
    const int t   = threadIdx.x;
    const int d   = t >> 5;   // 0..7  (feature within head)
    const int j   = t & 31;   // 0..31 (position lane)

    const float* hb   = h + (size_t)b * ((size_t)C_*L_) + (size_t)(hd*DH_)*L_ + (size_t)seg*SEG_;
    const float* rowd = hb + (size_t)d * L_;

    __shared__ float red[8][32];
    __shared__ float kred[8][8][32];

    // pass 1: per-d max over segment
    float m = -INFINITY;
    for (int k = j; k < SEG_; k += 32) m = fmaxf(m, rowd[k]);
    red[d][j] = m;
    __syncthreads();
    for (int off = 16; off > 0; off >>= 1){
        if (j < off) red[d][j] = fmaxf(red[d][j], red[d][j+off]);
        __syncthreads();
    }
    const float m_d = red[d][0];
    float m_mine = 0.0f;
    if (t < 8) m_mine = red[t][0];
    __syncthreads();

    // pass 2: sumexp + kv partials (unnormalized, referenced to segment max)
    float s = 0.0f;
    float kv[8];
    #pragma unroll
    for (int e = 0; e < 8; e++) kv[e] = 0.0f;
    for (int k = j; k < SEG_; k += 32){
        float ek = __expf(rowd[k] - m_d);
        s += ek;
        #pragma unroll
        for (int e = 0; e < 8; e++) kv[e] += ek * hb[(size_t)e*L_ + k];
    }
    red[d][j] = s;
    #pragma unroll
    for (int e = 0; e < 8; e++) kred[d][e][j] = kv[e];
    __syncthreads();

    float* po = part + (size_t)((b*H_ + hd)*S_ + seg) * 80;
    if (t < 8){
        float ss = 0.0f;
        for (int j2 = 0; j2 < 32; j2++) ss += red[t][j2];
        po[t]     = m_mine;
        po[8 + t] = ss;
    }
    if (t < 64){
        const int dd = t >> 3, ee = t & 7;
        float kk = 0.0f;
        for (int j2 = 0; j2 < 32; j2++) kk += kred[dd][ee][j2];
        po[16 + t] = kk;
    }
}

// ---- merge segment partials -> normalized kvn[b][head][d][e] = kv/s ----
__global__ __launch_bounds__(64) void merge_kernel(const float* __restrict__ part,
                                                   float* __restrict__ kvn){
    const int bh = blockIdx.x;      // 0..B*H-1
    const int t  = threadIdx.x;     // 0..63 -> (d,e)
    const int d  = t >> 3;
    const float* p = part + (size_t)bh * S_ * 80;
    float M = -INFINITY;
    for (int s2 = 0; s2 < S_; s2++) M = fmaxf(M, p[s2*80 + d]);
    float ssum = 0.0f, kvsum = 0.0f;
    for (int s2 = 0; s2 < S_; s2++){
        float sc = __expf(p[s2*80 + d] - M);
        ssum  += p[s2*80 + 8  + d] * sc;
        kvsum += p[s2*80 + 16 + t] * sc;
    }
    kvn[(size_t)bh*64 + t] = kvsum / ssum;
}

// ---- per-position: q-softmax, q@kvn, FC1+gelu, FC2+gelu; write h' or pool ----
// Weights/kvn staged in LDS; all weight reads are wave-uniform-address
// ds_read_b128 (broadcast, conflict-free). This keeps VMEM out of the inner
// loop entirely so the scheduler has no long-latency weight loads to hoist
// (R3: global weight loads -> VGPR pressure -> scratch spills, VGPR=40,
// ~38K VALU inst/wave vs ~4.6K useful).
template<bool LAST>
__global__ __launch_bounds__(256, 4) void block_kernel(const float* hin,
                                                    float* hout,
                                                    const float* __restrict__ kvn,
                                                    const float* __restrict__ W1,
                                                    const float* __restrict__ b1,
                                                    const float* __restrict__ W2,
                                                    const float* __restrict__ b2,
                                                    float* __restrict__ pooled){
    __shared__ float sW1[1024];
    __shared__ float sW2[1024];
    __shared__ float sb1[32];
    __shared__ float sb2[32];
    __shared__ float skv[256];

    const int b = blockIdx.y;
    const int l = blockIdx.x * 256 + threadIdx.x;
    const size_t base = (size_t)b * ((size_t)C_*L_);

    // stage weights + kvn into LDS (once per workgroup)
    for (int i = threadIdx.x; i < 1024; i += 256){
        sW1[i] = W1[i];
        sW2[i] = W2[i];
    }
    if (threadIdx.x < 32){
        sb1[threadIdx.x] = b1[threadIdx.x];
        sb2[threadIdx.x] = b2[threadIdx.x];
    }
    skv[threadIdx.x] = kvn[(size_t)b * (H_*DH_*DH_) + threadIdx.x];
    __syncthreads();

    float h[32];
    #pragma unroll
    for (int c = 0; c < 32; c++) h[c] = hin[base + (size_t)c*L_ + l];

    // per-head feature softmax + attn = q @ kvn
    float attn[32];
    #pragma unroll
    for (int hh = 0; hh < 4; hh++){
        float mq = h[hh*8];
        #pragma unroll
        for (int d2 = 1; d2 < 8; d2++) mq = fmaxf(mq, h[hh*8 + d2]);
        float es[8]; float qs = 0.f;
        #pragma unroll
        for (int d2 = 0; d2 < 8; d2++){ es[d2] = __expf(h[hh*8 + d2] - mq); qs += es[d2]; }
        const float inv = __builtin_amdgcn_rcpf(qs);
        float a[8];
        #pragma unroll
        for (int e = 0; e < 8; e++) a[e] = 0.f;
        #pragma unroll
        for (int d2 = 0; d2 < 8; d2++){
            const float4 w0 = *(const float4*)&skv[hh*64 + d2*8 + 0];
            const float4 w1 = *(const float4*)&skv[hh*64 + d2*8 + 4];
            a[0] = fmaf(es[d2], w0.x, a[0]);
            a[1] = fmaf(es[d2], w0.y, a[1]);
            a[2] = fmaf(es[d2], w0.z, a[2]);
            a[3] = fmaf(es[d2], w0.w, a[3]);
            a[4] = fmaf(es[d2], w1.x, a[4]);
            a[5] = fmaf(es[d2], w1.y, a[5]);
            a[6] = fmaf(es[d2], w1.z, a[6]);
            a[7] = fmaf(es[d2], w1.w, a[7]);
        }
        #pragma unroll
        for (int e = 0; e < 8; e++) attn[hh*8 + e] = a[e] * inv;
    }

    // FC1 + gelu (weights via wave-uniform ds_read_b128)
    float acc[32];
    #pragma unroll
    for (int c = 0; c < 32; c++) acc[c] = sb1[c];
    #pragma unroll
    for (int d2 = 0; d2 < 32; d2++){
        const float av = attn[d2];
        #pragma unroll
        for (int c4 = 0; c4 < 8; c4++){
            const float4 w = *(const float4*)&sW1[d2*32 + c4*4];
            acc[c4*4+0] = fmaf(av, w.x, acc[c4*4+0]);
            acc[c4*4+1] = fmaf(av, w.y, acc[c4*4+1]);
            acc[c4*4+2] = fmaf(av, w.z, acc[c4*4+2]);
            acc[c4*4+3] = fmaf(av, w.w, acc[c4*4+3]);
        }
    }
    float t1[32];
    #pragma unroll
    for (int c = 0; c < 32; c++) t1[c] = gelu_f(acc[c]);

    // FC2 + gelu
    #pragma unroll
    for (int c = 0; c < 32; c++) acc[c] = sb2[c];
    #pragma unroll
    for (int d2 = 0; d2 < 32; d2++){
        const float av = t1[d2];
        #pragma unroll
        for (int c4 = 0; c4 < 8; c4++){
            const float4 w = *(const float4*)&sW2[d2*32 + c4*4];
            acc[c4*4+0] = fmaf(av, w.x, acc[c4*4+0]);
            acc[c4*4+1] = fmaf(av, w.y, acc[c4*4+1]);
            acc[c4*4+2] = fmaf(av, w.z, acc[c4*4+2]);
            acc[c4*4+3] = fmaf(av, w.w, acc[c4*4+3]);
        }
    }
    #pragma unroll
    for (int c = 0; c < 32; c++) acc[c] = gelu_f(acc[c]);

    if (!LAST){
        #pragma unroll
        for (int c = 0; c < 32; c++) hout[base + (size_t)c*L_ + l] = acc[c];
    } else {
        __shared__ float pw[4][32];
        const int lane = threadIdx.x & 63;
        const int wave = threadIdx.x >> 6;
        #pragma unroll
        for (int c = 0; c < 32; c++){
            float v = acc[c];
            v += __shfl_xor(v, 32);
            v += __shfl_xor(v, 16);
            v += __shfl_xor(v, 8);
            v += __shfl_xor(v, 4);
            v += __shfl_xor(v, 2);
            v += __shfl_xor(v, 1);
            if (lane == 0) pw[wave][c] = v;
        }
        __syncthreads();
        if (threadIdx.x < 32){
            float v = pw[0][threadIdx.x] + pw[1][threadIdx.x]
                    + pw[2][threadIdx.x] + pw[3][threadIdx.x];
            atomicAdd(&pooled[b*32 + threadIdx.x], v);
        }
    }
}

// ---- head: pooled/L -> Wh+bh -> BN(eval) -> gelu -> Wf+bf ----
__global__ __launch_bounds__(1024) void head_kernel(const float* __restrict__ pooled,
                                                    const float* __restrict__ Wh,
                                                    const float* __restrict__ bh,
                                                    const float* __restrict__ gam,
                                                    const float* __restrict__ bet,
                                                    const float* __restrict__ mean,
                                                    const float* __restrict__ var,
                                                    const float* __restrict__ Wf,
                                                    const float* __restrict__ bf,
                                                    float* __restrict__ out){
    __shared__ float y2[32][32];
    const int t = threadIdx.x;      // 0..1023
    const int b = t >> 5, c = t & 31;
    float a = bh[c];
    const float invL = 1.0f / (float)L_;
    #pragma unroll
    for (int d = 0; d < 32; d++) a += (pooled[b*32 + d] * invL) * Wh[d*32 + c];
    a = (a - mean[c]) * rsqrtf(var[c] + 1e-5f) * gam[c] + bet[c];
    y2[b][c] = gelu_f(a);
    __syncthreads();
    if (t < B_*DOUT_){
        const int b2 = t / DOUT_, j = t % DOUT_;
        float r = bf[j];
        #pragma unroll
        for (int c2 = 0; c2 < 32; c2++) r += y2[b2][c2] * Wf[c2*DOUT_ + j];
        out[t] = r;
    }
}

extern "C" void kernel_launch(void* const* d_in, const int* in_sizes, int n_in,
                              void* d_out, int out_size, void* d_ws, size_t ws_size,
                              hipStream_t stream){
    (void)in_sizes; (void)n_in; (void)out_size; (void)ws_size;
    const float* x    = (const float*)d_in[0];
    const float* fW1  = (const float*)d_in[1];
    const float* fb1  = (const float*)d_in[2];
    const float* fW2  = (const float*)d_in[3];
    const float* fb2  = (const float*)d_in[4];
    const float* Wh   = (const float*)d_in[5];
    const float* bh   = (const float*)d_in[6];
    const float* gam  = (const float*)d_in[7];
    const float* bet  = (const float*)d_in[8];
    const float* mean = (const float*)d_in[9];
    const float* var  = (const float*)d_in[10];
    const float* Wf   = (const float*)d_in[11];
    const float* bf   = (const float*)d_in[12];
    float* out = (float*)d_out;

    float* hbuf   = (float*)d_ws;                          // B*C*L floats (64 MB)
    float* part   = hbuf + (size_t)B_*C_*L_;               // B*H*S*80
    float* kvn    = part + (size_t)B_*H_*S_*80;            // B*H*64
    float* pooled = kvn  + (size_t)B_*H_*64;               // B*C

    hipMemsetAsync(pooled, 0, B_*C_*sizeof(float), stream);

    dim3 sgrid(S_, H_, B_);
    dim3 bgrid(L_/256, B_);

    // block 0 (input = x, output -> hbuf)
    stats_kernel<<<sgrid, 256, 0, stream>>>(x, part);
    merge_kernel<<<B_*H_, 64, 0, stream>>>(part, kvn);
    block_kernel<false><<<bgrid, 256, 0, stream>>>(x, hbuf, kvn, fW1, fb1, fW2, fb2, nullptr);
    // block 1 (in-place on hbuf)
    stats_kernel<<<sgrid, 256, 0, stream>>>(hbuf, part);
    merge_kernel<<<B_*H_, 64, 0, stream>>>(part, kvn);
    block_kernel<false><<<bgrid, 256, 0, stream>>>(hbuf, hbuf, kvn,
        fW1 + C_*C_, fb1 + C_, fW2 + C_*C_, fb2 + C_, nullptr);
    // block 2 (no h write; reduce into pooled)
    stats_kernel<<<sgrid, 256, 0, stream>>>(hbuf, part);
    merge_kernel<<<B_*H_, 64, 0, stream>>>(part, kvn);
    block_kernel<true><<<bgrid, 256, 0, stream>>>(hbuf, nullptr, kvn,
        fW1 + 2*C_*C_, fb1 + 2*C_, fW2 + 2*C_*C_, fb2 + 2*C_, pooled);

    head_kernel<<<1, 1024, 0, stream>>>(pooled, Wh, bh, gam, bet, mean, var, Wf, bf, out);
}

// Round 5
// 669.134 us; speedup vs baseline: 2.8684x; 2.8684x over previous
//
#include <hip/hip_runtime.h>
#include <cstddef>

#define B_ 32
#define C_ 32
#define L_ 16384
#define H_ 4
#define DH_ 8
#define NB_ 3
#define DOUT_ 10
#define SEG_ 2048
#define S_ (L_/SEG_)   // 8 segments

// Branch-free gelu via Abramowitz-Stegun 7.1.26 erf approximation (|eps|<=1.5e-7).
__device__ __forceinline__ float gelu_f(float x){
    const float z  = fabsf(x) * 0.70710678118654752440f;
    const float t  = __builtin_amdgcn_rcpf(fmaf(0.3275911f, z, 1.0f));
    const float e  = __expf(-z * z);
    float p = fmaf(t, 1.061405429f, -1.453152027f);
    p = fmaf(t, p, 1.421413741f);
    p = fmaf(t, p, -0.284496736f);
    p = fmaf(t, p, 0.254829592f);
    const float erfz = 1.0f - p * t * e;          // erf(|x|/sqrt(2))
    const float phi  = fmaf(copysignf(erfz, x), 0.5f, 0.5f);
    return x * phi;
}

// ---- stats: per (b, head, seg) partial max / sumexp / kv over a 2048-pos segment ----
__global__ __launch_bounds__(256) void stats_kernel(const float* __restrict__ h,
                                                    float* __restrict__ part){
    const int seg = blockIdx.x;
    const int hd  = blockIdx.y;
    const int b   = blockIdx.z;
    const int t   = threadIdx.x;
    const int d   = t >> 5;   // 0..7  (feature within head)
    const int j   = t & 31;   // 0..31 (position lane)

    const float* hb   = h + (size_t)b * ((size_t)C_*L_) + (size_t)(hd*DH_)*L_ + (size_t)seg*SEG_;
    const float* rowd = hb + (size_t)d * L_;

    __shared__ float red[8][32];
    __shared__ float kred[8][8][32];

    // pass 1: per-d max over segment
    float m = -INFINITY;
    for (int k = j; k < SEG_; k += 32) m = fmaxf(m, rowd[k]);
    red[d][j] = m;
    __syncthreads();
    for (int off = 16; off > 0; off >>= 1){
        if (j < off) red[d][j] = fmaxf(red[d][j], red[d][j+off]);
        __syncthreads();
    }
    const float m_d = red[d][0];
    float m_mine = 0.0f;
    if (t < 8) m_mine = red[t][0];
    __syncthreads();

    // pass 2: sumexp + kv partials (unnormalized, referenced to segment max)
    float s = 0.0f;
    float kv[8];
    #pragma unroll
    for (int e = 0; e < 8; e++) kv[e] = 0.0f;
    for (int k = j; k < SEG_; k += 32){
        float ek = __expf(rowd[k] - m_d);
        s += ek;
        #pragma unroll
        for (int e = 0; e < 8; e++) kv[e] += ek * hb[(size_t)e*L_ + k];
    }
    red[d][j] = s;
    #pragma unroll
    for (int e = 0; e < 8; e++) kred[d][e][j] = kv[e];
    __syncthreads();

    float* po = part + (size_t)((b*H_ + hd)*S_ + seg) * 80;
    if (t < 8){
        float ss = 0.0f;
        for (int j2 = 0; j2 < 32; j2++) ss += red[t][j2];
        po[t]     = m_mine;
        po[8 + t] = ss;
    }
    if (t < 64){
        const int dd = t >> 3, ee = t & 7;
        float kk = 0.0f;
        for (int j2 = 0; j2 < 32; j2++) kk += kred[dd][ee][j2];
        po[16 + t] = kk;
    }
}

// ---- merge segment partials -> normalized kvn[b][head][d][e] = kv/s ----
__global__ __launch_bounds__(64) void merge_kernel(const float* __restrict__ part,
                                                   float* __restrict__ kvn){
    const int bh = blockIdx.x;      // 0..B*H-1
    const int t  = threadIdx.x;     // 0..63 -> (d,e)
    const int d  = t >> 3;
    const float* p = part + (size_t)bh * S_ * 80;
    float M = -INFINITY;
    for (int s2 = 0; s2 < S_; s2++) M = fmaxf(M, p[s2*80 + d]);
    float ssum = 0.0f, kvsum = 0.0f;
    for (int s2 = 0; s2 < S_; s2++){
        float sc = __expf(p[s2*80 + d] - M);
        ssum  += p[s2*80 + 8  + d] * sc;
        kvsum += p[s2*80 + 16 + t] * sc;
    }
    kvn[(size_t)bh*64 + t] = kvsum / ssum;
}

// ---- per-position: q-softmax, q@kvn, FC1+gelu, FC2+gelu; write h' or pool ----
// amdgpu_waves_per_eu(4,4): pin the allocator's occupancy TARGET to 4
// waves/EU (VGPR budget 128). __launch_bounds__' 2nd arg only sets a MINIMUM
// waves/EU; LLVM's memory-bound heuristic still targeted 8 waves (<=64 VGPR)
// and spilled h/attn/acc/t1 to scratch (R4: 5.8 GB HBM scratch traffic,
// VALUBusy 3.5%). Weights stay as global loads with block-uniform indices ->
// scalar s_load + v_fmac v,s,v (no VGPR cost, scalar pipe).
template<bool LAST>
__global__ __launch_bounds__(256)
__attribute__((amdgpu_waves_per_eu(4, 4)))
void block_kernel(const float* hin,
                  float* hout,
                  const float* __restrict__ kvn,
                  const float* __restrict__ W1,
                  const float* __restrict__ b1,
                  const float* __restrict__ W2,
                  const float* __restrict__ b2,
                  float* __restrict__ pooled){
    const int b = blockIdx.y;
    const int l = blockIdx.x * 256 + threadIdx.x;
    const size_t base = (size_t)b * ((size_t)C_*L_);
    const float* kv = kvn + (size_t)b * (H_*DH_*DH_);

    float h[32];
    #pragma unroll
    for (int c = 0; c < 32; c++) h[c] = hin[base + (size_t)c*L_ + l];

    // per-head feature softmax + attn = q @ kvn
    float attn[32];
    #pragma unroll
    for (int hh = 0; hh < 4; hh++){
        float mq = h[hh*8];
        #pragma unroll
        for (int d2 = 1; d2 < 8; d2++) mq = fmaxf(mq, h[hh*8 + d2]);
        float es[8]; float qs = 0.f;
        #pragma unroll
        for (int d2 = 0; d2 < 8; d2++){ es[d2] = __expf(h[hh*8 + d2] - mq); qs += es[d2]; }
        const float inv = __builtin_amdgcn_rcpf(qs);
        #pragma unroll
        for (int e = 0; e < 8; e++){
            float a = 0.f;
            #pragma unroll
            for (int d2 = 0; d2 < 8; d2++) a += es[d2] * kv[hh*64 + d2*8 + e];
            attn[hh*8 + e] = a * inv;
        }
    }

    // FC1 + gelu
    float acc[32];
    #pragma unroll
    for (int c = 0; c < 32; c++) acc[c] = b1[c];
    #pragma unroll
    for (int d2 = 0; d2 < 32; d2++){
        const float av = attn[d2];
        #pragma unroll
        for (int c = 0; c < 32; c++) acc[c] = fmaf(av, W1[d2*32 + c], acc[c]);
    }
    float t1[32];
    #pragma unroll
    for (int c = 0; c < 32; c++) t1[c] = gelu_f(acc[c]);

    // FC2 + gelu
    #pragma unroll
    for (int c = 0; c < 32; c++) acc[c] = b2[c];
    #pragma unroll
    for (int d2 = 0; d2 < 32; d2++){
        const float av = t1[d2];
        #pragma unroll
        for (int c = 0; c < 32; c++) acc[c] = fmaf(av, W2[d2*32 + c], acc[c]);
    }
    #pragma unroll
    for (int c = 0; c < 32; c++) acc[c] = gelu_f(acc[c]);

    if (!LAST){
        #pragma unroll
        for (int c = 0; c < 32; c++) hout[base + (size_t)c*L_ + l] = acc[c];
    } else {
        __shared__ float pw[4][32];
        const int lane = threadIdx.x & 63;
        const int wave = threadIdx.x >> 6;
        #pragma unroll
        for (int c = 0; c < 32; c++){
            float v = acc[c];
            v += __shfl_xor(v, 32);
            v += __shfl_xor(v, 16);
            v += __shfl_xor(v, 8);
            v += __shfl_xor(v, 4);
            v += __shfl_xor(v, 2);
            v += __shfl_xor(v, 1);
            if (lane == 0) pw[wave][c] = v;
        }
        __syncthreads();
        if (threadIdx.x < 32){
            float v = pw[0][threadIdx.x] + pw[1][threadIdx.x]
                    + pw[2][threadIdx.x] + pw[3][threadIdx.x];
            atomicAdd(&pooled[b*32 + threadIdx.x], v);
        }
    }
}

// ---- head: pooled/L -> Wh+bh -> BN(eval) -> gelu -> Wf+bf ----
__global__ __launch_bounds__(1024) void head_kernel(const float* __restrict__ pooled,
                                                    const float* __restrict__ Wh,
                                                    const float* __restrict__ bh,
                                                    const float* __restrict__ gam,
                                                    const float* __restrict__ bet,
                                                    const float* __restrict__ mean,
                                                    const float* __restrict__ var,
                                                    const float* __restrict__ Wf,
                                                    const float* __restrict__ bf,
                                                    float* __restrict__ out){
    __shared__ float y2[32][32];
    const int t = threadIdx.x;      // 0..1023
    const int b = t >> 5, c = t & 31;
    float a = bh[c];
    const float invL = 1.0f / (float)L_;
    #pragma unroll
    for (int d = 0; d < 32; d++) a += (pooled[b*32 + d] * invL) * Wh[d*32 + c];
    a = (a - mean[c]) * rsqrtf(var[c] + 1e-5f) * gam[c] + bet[c];
    y2[b][c] = gelu_f(a);
    __syncthreads();
    if (t < B_*DOUT_){
        const int b2 = t / DOUT_, j = t % DOUT_;
        float r = bf[j];
        #pragma unroll
        for (int c2 = 0; c2 < 32; c2++) r += y2[b2][c2] * Wf[c2*DOUT_ + j];
        out[t] = r;
    }
}

extern "C" void kernel_launch(void* const* d_in, const int* in_sizes, int n_in,
                              void* d_out, int out_size, void* d_ws, size_t ws_size,
                              hipStream_t stream){
    (void)in_sizes; (void)n_in; (void)out_size; (void)ws_size;
    const float* x    = (const float*)d_in[0];
    const float* fW1  = (const float*)d_in[1];
    const float* fb1  = (const float*)d_in[2];
    const float* fW2  = (const float*)d_in[3];
    const float* fb2  = (const float*)d_in[4];
    const float* Wh   = (const float*)d_in[5];
    const float* bh   = (const float*)d_in[6];
    const float* gam  = (const float*)d_in[7];
    const float* bet  = (const float*)d_in[8];
    const float* mean = (const float*)d_in[9];
    const float* var  = (const float*)d_in[10];
    const float* Wf   = (const float*)d_in[11];
    const float* bf   = (const float*)d_in[12];
    float* out = (float*)d_out;

    float* hbuf   = (float*)d_ws;                          // B*C*L floats (64 MB)
    float* part   = hbuf + (size_t)B_*C_*L_;               // B*H*S*80
    float* kvn    = part + (size_t)B_*H_*S_*80;            // B*H*64
    float* pooled = kvn  + (size_t)B_*H_*64;               // B*C

    hipMemsetAsync(pooled, 0, B_*C_*sizeof(float), stream);

    dim3 sgrid(S_, H_, B_);
    dim3 bgrid(L_/256, B_);

    // block 0 (input = x, output -> hbuf)
    stats_kernel<<<sgrid, 256, 0, stream>>>(x, part);
    merge_kernel<<<B_*H_, 64, 0, stream>>>(part, kvn);
    block_kernel<false><<<bgrid, 256, 0, stream>>>(x, hbuf, kvn, fW1, fb1, fW2, fb2, nullptr);
    // block 1 (in-place on hbuf)
    stats_kernel<<<sgrid, 256, 0, stream>>>(hbuf, part);
    merge_kernel<<<B_*H_, 64, 0, stream>>>(part, kvn);
    block_kernel<false><<<bgrid, 256, 0, stream>>>(hbuf, hbuf, kvn,
        fW1 + C_*C_, fb1 + C_, fW2 + C_*C_, fb2 + C_, nullptr);
    // block 2 (no h write; reduce into pooled)
    stats_kernel<<<sgrid, 256, 0, stream>>>(hbuf, part);
    merge_kernel<<<B_*H_, 64, 0, stream>>>(part, kvn);
    block_kernel<true><<<bgrid, 256, 0, stream>>>(hbuf, nullptr, kvn,
        fW1 + 2*C_*C_, fb1 + 2*C_, fW2 + 2*C_*C_, fb2 + 2*C_, pooled);

    head_kernel<<<1, 1024, 0, stream>>>(pooled, Wh, bh, gam, bet, mean, var, Wf, bf, out);
}

// Round 6
// 354.900 us; speedup vs baseline: 5.4081x; 1.8854x over previous
//
#include <hip/hip_runtime.h>
#include <cstddef>

#define B_ 32
#define C_ 32
#define L_ 16384
#define H_ 4
#define DH_ 8
#define NB_ 3
#define DOUT_ 10
#define SEG_ 2048
#define S_ (L_/SEG_)   // 8 segments

#define TILE 256
#define AST  40    // A_lds row stride (halfs): 80 B/row -> 16B-aligned b128 frag reads
#define OST  260   // O16 row stride (floats): 16B-aligned f32x4, banks spread by +4

typedef _Float16 f16_t;
typedef _Float16 f16x2 __attribute__((ext_vector_type(2)));
typedef _Float16 f16x8 __attribute__((ext_vector_type(8)));
typedef float    f32x4 __attribute__((ext_vector_type(4)));

// Branch-free gelu via Abramowitz-Stegun 7.1.26 erf approximation (|eps|<=1.5e-7).
__device__ __forceinline__ float gelu_f(float x){
    const float z  = fabsf(x) * 0.70710678118654752440f;
    const float t  = __builtin_amdgcn_rcpf(fmaf(0.3275911f, z, 1.0f));
    const float e  = __expf(-z * z);
    float p = fmaf(t, 1.061405429f, -1.453152027f);
    p = fmaf(t, p, 1.421413741f);
    p = fmaf(t, p, -0.284496736f);
    p = fmaf(t, p, 0.254829592f);
    const float erfz = 1.0f - p * t * e;          // erf(|x|/sqrt(2))
    const float phi  = fmaf(copysignf(erfz, x), 0.5f, 0.5f);
    return x * phi;
}

// ---- stats: per (b, head, seg) partial max / sumexp / kv over a 2048-pos segment ----
__global__ __launch_bounds__(256) void stats_kernel(const float* __restrict__ h,
                                                    float* __restrict__ part){
    const int seg = blockIdx.x;
    const int hd  = blockIdx.y;
    const int b   = blockIdx.z;
    const int t   = threadIdx.x;
    const int d   = t >> 5;   // 0..7  (feature within head)
    const int j   = t & 31;   // 0..31 (position lane)

    const float* hb   = h + (size_t)b * ((size_t)C_*L_) + (size_t)(hd*DH_)*L_ + (size_t)seg*SEG_;
    const float* rowd = hb + (size_t)d * L_;

    __shared__ float red[8][32];
    __shared__ float kred[8][8][32];

    // pass 1: per-d max over segment
    float m = -INFINITY;
    for (int k = j; k < SEG_; k += 32) m = fmaxf(m, rowd[k]);
    red[d][j] = m;
    __syncthreads();
    for (int off = 16; off > 0; off >>= 1){
        if (j < off) red[d][j] = fmaxf(red[d][j], red[d][j+off]);
        __syncthreads();
    }
    const float m_d = red[d][0];
    float m_mine = 0.0f;
    if (t < 8) m_mine = red[t][0];
    __syncthreads();

    // pass 2: sumexp + kv partials (unnormalized, referenced to segment max)
    float s = 0.0f;
    float kv[8];
    #pragma unroll
    for (int e = 0; e < 8; e++) kv[e] = 0.0f;
    for (int k = j; k < SEG_; k += 32){
        float ek = __expf(rowd[k] - m_d);
        s += ek;
        #pragma unroll
        for (int e = 0; e < 8; e++) kv[e] += ek * hb[(size_t)e*L_ + k];
    }
    red[d][j] = s;
    #pragma unroll
    for (int e = 0; e < 8; e++) kred[d][e][j] = kv[e];
    __syncthreads();

    float* po = part + (size_t)((b*H_ + hd)*S_ + seg) * 80;
    if (t < 8){
        float ss = 0.0f;
        for (int j2 = 0; j2 < 32; j2++) ss += red[t][j2];
        po[t]     = m_mine;
        po[8 + t] = ss;
    }
    if (t < 64){
        const int dd = t >> 3, ee = t & 7;
        float kk = 0.0f;
        for (int j2 = 0; j2 < 32; j2++) kk += kred[dd][ee][j2];
        po[16 + t] = kk;
    }
}

// ---- merge segment partials -> normalized kvn[b][head][d][e] = kv/s ----
__global__ __launch_bounds__(64) void merge_kernel(const float* __restrict__ part,
                                                   float* __restrict__ kvn){
    const int bh = blockIdx.x;      // 0..B*H-1
    const int t  = threadIdx.x;     // 0..63 -> (d,e)
    const int d  = t >> 3;
    const float* p = part + (size_t)bh * S_ * 80;
    float M = -INFINITY;
    for (int s2 = 0; s2 < S_; s2++) M = fmaxf(M, p[s2*80 + d]);
    float ssum = 0.0f, kvsum = 0.0f;
    for (int s2 = 0; s2 < S_; s2++){
        float sc = __expf(p[s2*80 + d] - M);
        ssum  += p[s2*80 + 8  + d] * sc;
        kvsum += p[s2*80 + 16 + t] * sc;
    }
    kvn[(size_t)bh*64 + t] = kvsum / ssum;
}

// ---- per-position attention (fp32) + FC1/FC2 via f16 MFMA ----
// Workgroup = 256 positions of one batch. FCs are [256x32]@[32x32] GEMMs:
// per wave 8x v_mfma_f32_16x16x32_f16 per FC replaces ~2048 scalar-weight
// v_fmac + strided s_loads (R3/R5 plateau: compiler's register-lean FC
// structure was SMEM/issue-bound, ~6x over VALU floor).
// MFMA layouts (m89/m91-verified conventions):
//   A-frag: lane holds A[m=lane&15][k=(lane>>4)*8+j], 8 halfs contiguous
//   B-frag: lane holds B[k=(lane>>4)*8+j][n=lane&15]  (stored as Bsh[n][k])
//   C/D:    col=lane&15, row=(lane>>4)*4+reg
template<bool LAST>
__global__ __launch_bounds__(256)
__attribute__((amdgpu_waves_per_eu(3, 4)))
void block_kernel(const float* hin,
                  float* hout,
                  const float* __restrict__ kvn,
                  const float* __restrict__ W1,
                  const float* __restrict__ b1,
                  const float* __restrict__ W2,
                  const float* __restrict__ b2,
                  float* __restrict__ pooled){
    __shared__ f16_t Ash[TILE*AST];     // 20480 B: A matrix [pos][k] halfs
    __shared__ f16_t Bsh1[32*AST];      // 2560 B: W1 as [n][k]
    __shared__ f16_t Bsh2[32*AST];      // 2560 B
    __shared__ float sb1[32], sb2[32];
    __shared__ float O16[16*OST];       // 16640 B: transpose buffer, 16 chans
    __shared__ float pool[32];

    const int tid = threadIdx.x;
    const int b   = blockIdx.y;
    const int l0  = blockIdx.x * TILE;
    const int l   = l0 + tid;
    const size_t base = (size_t)b * ((size_t)C_*L_);
    const float* kv = kvn + (size_t)b * (H_*DH_*DH_);

    // stage weights f32->f16 into B-layout: Bsh[n][k] = W[k*32+n]
    for (int i = tid; i < 1024; i += 256){
        const int k = i >> 5, n = i & 31;
        Bsh1[n*AST + k] = (f16_t)W1[i];
        Bsh2[n*AST + k] = (f16_t)W2[i];
    }
    if (tid < 32){ sb1[tid] = b1[tid]; sb2[tid] = b2[tid]; }
    if (LAST && tid < 32) pool[tid] = 0.0f;

    // ---- phase 1: per-thread fp32 attention ----
    float h[32];
    #pragma unroll
    for (int c = 0; c < 32; c++) h[c] = hin[base + (size_t)c*L_ + l];

    float attn[32];
    #pragma unroll
    for (int hh = 0; hh < 4; hh++){
        float mq = h[hh*8];
        #pragma unroll
        for (int d2 = 1; d2 < 8; d2++) mq = fmaxf(mq, h[hh*8 + d2]);
        float es[8]; float qs = 0.f;
        #pragma unroll
        for (int d2 = 0; d2 < 8; d2++){ es[d2] = __expf(h[hh*8 + d2] - mq); qs += es[d2]; }
        const float inv = __builtin_amdgcn_rcpf(qs);
        #pragma unroll
        for (int e = 0; e < 8; e++){
            float a = 0.f;
            #pragma unroll
            for (int d2 = 0; d2 < 8; d2++) a += es[d2] * kv[hh*64 + d2*8 + e];
            attn[hh*8 + e] = a * inv;
        }
    }

    // attn -> f16 A matrix in LDS: Ash[pos=tid][k]
    #pragma unroll
    for (int k2 = 0; k2 < 32; k2 += 2){
        f16x2 pr = { (f16_t)attn[k2], (f16_t)attn[k2+1] };
        *(f16x2*)&Ash[tid*AST + k2] = pr;
    }
    __syncthreads();   // weights + A visible to all

    // ---- phase 2: MFMA FCs ----
    const int wv   = tid >> 6;       // wave 0..3 -> positions [wv*64, wv*64+64)
    const int lane = tid & 63;
    const int lr   = lane & 15;      // A-row / D-col index
    const int lk   = lane >> 4;      // k-group 0..3
    const f32x4 zero = {0.f, 0.f, 0.f, 0.f};

    f16x8 a[4], bw[2];
    f32x4 d[8];

    // FC1
    #pragma unroll
    for (int mt = 0; mt < 4; mt++)
        a[mt] = *(const f16x8*)&Ash[(wv*64 + mt*16 + lr)*AST + lk*8];
    #pragma unroll
    for (int nt = 0; nt < 2; nt++)
        bw[nt] = *(const f16x8*)&Bsh1[(nt*16 + lr)*AST + lk*8];
    #pragma unroll
    for (int nt = 0; nt < 2; nt++)
        #pragma unroll
        for (int mt = 0; mt < 4; mt++)
            d[nt*4+mt] = __builtin_amdgcn_mfma_f32_16x16x32_f16(a[mt], bw[nt], zero, 0, 0, 0);

    // bias + gelu + write back as A2 (in-place over Ash; rows are wave-private)
    #pragma unroll
    for (int nt = 0; nt < 2; nt++){
        const float bias = sb1[nt*16 + lr];
        #pragma unroll
        for (int mt = 0; mt < 4; mt++){
            #pragma unroll
            for (int r = 0; r < 4; r++){
                const float v = gelu_f(d[nt*4+mt][r] + bias);
                Ash[(wv*64 + mt*16 + lk*4 + r)*AST + (nt*16 + lr)] = (f16_t)v;
            }
        }
    }
    __syncthreads();

    // FC2
    #pragma unroll
    for (int mt = 0; mt < 4; mt++)
        a[mt] = *(const f16x8*)&Ash[(wv*64 + mt*16 + lr)*AST + lk*8];
    #pragma unroll
    for (int nt = 0; nt < 2; nt++)
        bw[nt] = *(const f16x8*)&Bsh2[(nt*16 + lr)*AST + lk*8];
    #pragma unroll
    for (int nt = 0; nt < 2; nt++)
        #pragma unroll
        for (int mt = 0; mt < 4; mt++)
            d[nt*4+mt] = __builtin_amdgcn_mfma_f32_16x16x32_f16(a[mt], bw[nt], zero, 0, 0, 0);

    // bias + gelu on D (fp32)
    #pragma unroll
    for (int nt = 0; nt < 2; nt++){
        const float bias = sb2[nt*16 + lr];
        #pragma unroll
        for (int mt = 0; mt < 4; mt++)
            #pragma unroll
            for (int r = 0; r < 4; r++)
                d[nt*4+mt][r] = gelu_f(d[nt*4+mt][r] + bias);
    }

    if (!LAST){
        // transpose D -> [chan][pos] via LDS, 16 channels per half, coalesced stores
        #pragma unroll
        for (int nt = 0; nt < 2; nt++){
            __syncthreads();
            #pragma unroll
            for (int mt = 0; mt < 4; mt++)
                *(f32x4*)&O16[lr*OST + wv*64 + mt*16 + lk*4] = d[nt*4+mt];
            __syncthreads();
            #pragma unroll
            for (int c = 0; c < 16; c++)
                hout[base + (size_t)(nt*16 + c)*L_ + l0 + tid] = O16[c*OST + tid];
        }
    } else {
        // pooled += sum over this WG's 256 positions
        __syncthreads();   // pool[] initialized
        #pragma unroll
        for (int nt = 0; nt < 2; nt++){
            float ps = 0.f;
            #pragma unroll
            for (int mt = 0; mt < 4; mt++)
                ps += d[nt*4+mt][0] + d[nt*4+mt][1] + d[nt*4+mt][2] + d[nt*4+mt][3];
            atomicAdd(&pool[nt*16 + lr], ps);
        }
        __syncthreads();
        if (tid < 32) atomicAdd(&pooled[b*32 + tid], pool[tid]);
    }
}

// ---- head: pooled/L -> Wh+bh -> BN(eval) -> gelu -> Wf+bf ----
__global__ __launch_bounds__(1024) void head_kernel(const float* __restrict__ pooled,
                                                    const float* __restrict__ Wh,
                                                    const float* __restrict__ bh,
                                                    const float* __restrict__ gam,
                                                    const float* __restrict__ bet,
                                                    const float* __restrict__ mean,
                                                    const float* __restrict__ var,
                                                    const float* __restrict__ Wf,
                                                    const float* __restrict__ bf,
                                                    float* __restrict__ out){
    __shared__ float y2[32][32];
    const int t = threadIdx.x;      // 0..1023
    const int b = t >> 5, c = t & 31;
    float a = bh[c];
    const float invL = 1.0f / (float)L_;
    #pragma unroll
    for (int d = 0; d < 32; d++) a += (pooled[b*32 + d] * invL) * Wh[d*32 + c];
    a = (a - mean[c]) * rsqrtf(var[c] + 1e-5f) * gam[c] + bet[c];
    y2[b][c] = gelu_f(a);
    __syncthreads();
    if (t < B_*DOUT_){
        const int b2 = t / DOUT_, j = t % DOUT_;
        float r = bf[j];
        #pragma unroll
        for (int c2 = 0; c2 < 32; c2++) r += y2[b2][c2] * Wf[c2*DOUT_ + j];
        out[t] = r;
    }
}

extern "C" void kernel_launch(void* const* d_in, const int* in_sizes, int n_in,
                              void* d_out, int out_size, void* d_ws, size_t ws_size,
                              hipStream_t stream){
    (void)in_sizes; (void)n_in; (void)out_size; (void)ws_size;
    const float* x    = (const float*)d_in[0];
    const float* fW1  = (const float*)d_in[1];
    const float* fb1  = (const float*)d_in[2];
    const float* fW2  = (const float*)d_in[3];
    const float* fb2  = (const float*)d_in[4];
    const float* Wh   = (const float*)d_in[5];
    const float* bh   = (const float*)d_in[6];
    const float* gam  = (const float*)d_in[7];
    const float* bet  = (const float*)d_in[8];
    const float* mean = (const float*)d_in[9];
    const float* var  = (const float*)d_in[10];
    const float* Wf   = (const float*)d_in[11];
    const float* bf   = (const float*)d_in[12];
    float* out = (float*)d_out;

    float* hbuf   = (float*)d_ws;                          // B*C*L floats (64 MB)
    float* part   = hbuf + (size_t)B_*C_*L_;               // B*H*S*80
    float* kvn    = part + (size_t)B_*H_*S_*80;            // B*H*64
    float* pooled = kvn  + (size_t)B_*H_*64;               // B*C

    hipMemsetAsync(pooled, 0, B_*C_*sizeof(float), stream);

    dim3 sgrid(S_, H_, B_);
    dim3 bgrid(L_/TILE, B_);

    // block 0 (input = x, output -> hbuf)
    stats_kernel<<<sgrid, 256, 0, stream>>>(x, part);
    merge_kernel<<<B_*H_, 64, 0, stream>>>(part, kvn);
    block_kernel<false><<<bgrid, 256, 0, stream>>>(x, hbuf, kvn, fW1, fb1, fW2, fb2, nullptr);
    // block 1 (in-place on hbuf)
    stats_kernel<<<sgrid, 256, 0, stream>>>(hbuf, part);
    merge_kernel<<<B_*H_, 64, 0, stream>>>(part, kvn);
    block_kernel<false><<<bgrid, 256, 0, stream>>>(hbuf, hbuf, kvn,
        fW1 + C_*C_, fb1 + C_, fW2 + C_*C_, fb2 + C_, nullptr);
    // block 2 (no h write; reduce into pooled)
    stats_kernel<<<sgrid, 256, 0, stream>>>(hbuf, part);
    merge_kernel<<<B_*H_, 64, 0, stream>>>(part, kvn);
    block_kernel<true><<<bgrid, 256, 0, stream>>>(hbuf, nullptr, kvn,
        fW1 + 2*C_*C_, fb1 + 2*C_, fW2 + 2*C_*C_, fb2 + 2*C_, pooled);

    head_kernel<<<1, 1024, 0, stream>>>(pooled, Wh, bh, gam, bet, mean, var, Wf, bf, out);
}

// Round 7
// 290.390 us; speedup vs baseline: 6.6096x; 1.2222x over previous
//
#include <hip/hip_runtime.h>
#include <cstddef>

#define B_ 32
#define C_ 32
#define L_ 16384
#define H_ 4
#define DH_ 8
#define NB_ 3
#define DOUT_ 10
#define SEG_ 512
#define S_ (L_/SEG_)   // 32 segments

#define TILE 256
#define AST  40    // A_lds row stride (halfs): 80 B/row -> 16B-aligned b128 frag reads
#define OST  260   // O16 row stride (floats): 16B-aligned f32x4, banks spread by +4

typedef _Float16 f16_t;
typedef _Float16 f16x2 __attribute__((ext_vector_type(2)));
typedef _Float16 f16x8 __attribute__((ext_vector_type(8)));
typedef float    f32x4 __attribute__((ext_vector_type(4)));

// Branch-free gelu via Abramowitz-Stegun 7.1.26 erf approximation (|eps|<=1.5e-7).
__device__ __forceinline__ float gelu_f(float x){
    const float z  = fabsf(x) * 0.70710678118654752440f;
    const float t  = __builtin_amdgcn_rcpf(fmaf(0.3275911f, z, 1.0f));
    const float e  = __expf(-z * z);
    float p = fmaf(t, 1.061405429f, -1.453152027f);
    p = fmaf(t, p, 1.421413741f);
    p = fmaf(t, p, -0.284496736f);
    p = fmaf(t, p, 0.254829592f);
    const float erfz = 1.0f - p * t * e;          // erf(|x|/sqrt(2))
    const float phi  = fmaf(copysignf(erfz, x), 0.5f, 0.5f);
    return x * phi;
}

// ---- stats: per (b, head, seg) partial max / sumexp / kv over a 512-pos segment ----
// R6 version (SEG=2048) was latency-bound: 1024 WGs (25% occ) x 9 dependent
// global loads/iter -> 58 us @ 27% VALUBusy. Now: 4096 WGs (full occupancy),
// tile staged once to LDS via float4 (1 global touch per element), all inner
// reads are stride-1 ds_read_b32 (2-way wave aliasing = free). Per-d max
// reduces with 5 shfl_xor since each wave-half owns one d row.
__global__ __launch_bounds__(256) void stats_kernel(const float* __restrict__ h,
                                                    float* __restrict__ part){
    const int seg = blockIdx.x;
    const int hd  = blockIdx.y;
    const int b   = blockIdx.z;
    const int t   = threadIdx.x;
    const int d   = t >> 5;   // 0..7  (feature within head); wave-half owns one d
    const int j   = t & 31;   // 0..31 (position lane)

    __shared__ float tile[8][SEG_];   // 16 KB
    __shared__ float sm[8];

    const float* hb = h + (size_t)b * ((size_t)C_*L_) + (size_t)(hd*DH_)*L_ + (size_t)seg*SEG_;

    // stage 8 x 512 tile (coalesced float4; each element fetched exactly once)
    for (int f = t; f < 8*SEG_/4; f += 256){
        const int row = f >> 7;            // 128 float4 per row
        const int c4  = (f & 127) << 2;
        *(f32x4*)&tile[row][c4] = *(const f32x4*)&hb[(size_t)row*L_ + c4];
    }
    __syncthreads();

    // pass 1: per-d max (intra-half shuffle reduce; half == all j's of this d)
    float m = -INFINITY;
    #pragma unroll
    for (int i = 0; i < SEG_/32; i++) m = fmaxf(m, tile[d][j + 32*i]);
    m = fmaxf(m, __shfl_xor(m, 1));
    m = fmaxf(m, __shfl_xor(m, 2));
    m = fmaxf(m, __shfl_xor(m, 4));
    m = fmaxf(m, __shfl_xor(m, 8));
    m = fmaxf(m, __shfl_xor(m, 16));
    if (j == 0) sm[d] = m;
    const float m_d = m;

    // pass 2: sumexp + kv partials (referenced to segment max)
    float s = 0.0f;
    float kv[8];
    #pragma unroll
    for (int e = 0; e < 8; e++) kv[e] = 0.0f;
    #pragma unroll
    for (int i = 0; i < SEG_/32; i++){
        const int k = j + 32*i;
        const float ek = __expf(tile[d][k] - m_d);
        s += ek;
        #pragma unroll
        for (int e = 0; e < 8; e++) kv[e] = fmaf(ek, tile[e][k], kv[e]);
    }
    // reduce s and kv over the 32 j-lanes of this half
    s += __shfl_xor(s, 1);  s += __shfl_xor(s, 2);  s += __shfl_xor(s, 4);
    s += __shfl_xor(s, 8);  s += __shfl_xor(s, 16);
    #pragma unroll
    for (int e = 0; e < 8; e++){
        kv[e] += __shfl_xor(kv[e], 1);  kv[e] += __shfl_xor(kv[e], 2);
        kv[e] += __shfl_xor(kv[e], 4);  kv[e] += __shfl_xor(kv[e], 8);
        kv[e] += __shfl_xor(kv[e], 16);
    }
    __syncthreads();

    float* po = part + (size_t)((b*H_ + hd)*S_ + seg) * 80;
    if (j == 0){
        po[8 + d] = s;
        #pragma unroll
        for (int e = 0; e < 8; e++) po[16 + d*8 + e] = kv[e];
    }
    if (t < 8) po[t] = sm[t];
}

// ---- merge segment partials -> normalized kvn[b][head][d][e] = kv/s ----
__global__ __launch_bounds__(64) void merge_kernel(const float* __restrict__ part,
                                                   float* __restrict__ kvn){
    const int bh = blockIdx.x;      // 0..B*H-1
    const int t  = threadIdx.x;     // 0..63 -> (d,e)
    const int d  = t >> 3;
    const float* p = part + (size_t)bh * S_ * 80;
    float M = -INFINITY;
    for (int s2 = 0; s2 < S_; s2++) M = fmaxf(M, p[s2*80 + d]);
    float ssum = 0.0f, kvsum = 0.0f;
    for (int s2 = 0; s2 < S_; s2++){
        float sc = __expf(p[s2*80 + d] - M);
        ssum  += p[s2*80 + 8  + d] * sc;
        kvsum += p[s2*80 + 16 + t] * sc;
    }
    kvn[(size_t)bh*64 + t] = kvsum / ssum;
}

// ---- per-position attention (fp32) + FC1/FC2 via f16 MFMA ----
// Workgroup = 256 positions of one batch. FCs are [256x32]@[32x32] GEMMs:
// per wave 8x v_mfma_f32_16x16x32_f16 per FC replaces ~2048 scalar-weight
// v_fmac + strided s_loads (R3/R5 plateau: compiler's register-lean FC
// structure was SMEM/issue-bound, ~6x over VALU floor).
// MFMA layouts (m89/m91-verified conventions):
//   A-frag: lane holds A[m=lane&15][k=(lane>>4)*8+j], 8 halfs contiguous
//   B-frag: lane holds B[k=(lane>>4)*8+j][n=lane&15]  (stored as Bsh[n][k])
//   C/D:    col=lane&15, row=(lane>>4)*4+reg
template<bool LAST>
__global__ __launch_bounds__(256)
__attribute__((amdgpu_waves_per_eu(3, 4)))
void block_kernel(const float* hin,
                  float* hout,
                  const float* __restrict__ kvn,
                  const float* __restrict__ W1,
                  const float* __restrict__ b1,
                  const float* __restrict__ W2,
                  const float* __restrict__ b2,
                  float* __restrict__ pooled){
    __shared__ f16_t Ash[TILE*AST];     // 20480 B: A matrix [pos][k] halfs
    __shared__ f16_t Bsh1[32*AST];      // 2560 B: W1 as [n][k]
    __shared__ f16_t Bsh2[32*AST];      // 2560 B
    __shared__ float sb1[32], sb2[32];
    __shared__ float O16[16*OST];       // 16640 B: transpose buffer, 16 chans
    __shared__ float pool[32];

    const int tid = threadIdx.x;
    const int b   = blockIdx.y;
    const int l0  = blockIdx.x * TILE;
    const int l   = l0 + tid;
    const size_t base = (size_t)b * ((size_t)C_*L_);
    const float* kv = kvn + (size_t)b * (H_*DH_*DH_);

    // stage weights f32->f16 into B-layout: Bsh[n][k] = W[k*32+n]
    for (int i = tid; i < 1024; i += 256){
        const int k = i >> 5, n = i & 31;
        Bsh1[n*AST + k] = (f16_t)W1[i];
        Bsh2[n*AST + k] = (f16_t)W2[i];
    }
    if (tid < 32){ sb1[tid] = b1[tid]; sb2[tid] = b2[tid]; }
    if (LAST && tid < 32) pool[tid] = 0.0f;

    // ---- phase 1: per-thread fp32 attention ----
    float h[32];
    #pragma unroll
    for (int c = 0; c < 32; c++) h[c] = hin[base + (size_t)c*L_ + l];

    float attn[32];
    #pragma unroll
    for (int hh = 0; hh < 4; hh++){
        float mq = h[hh*8];
        #pragma unroll
        for (int d2 = 1; d2 < 8; d2++) mq = fmaxf(mq, h[hh*8 + d2]);
        float es[8]; float qs = 0.f;
        #pragma unroll
        for (int d2 = 0; d2 < 8; d2++){ es[d2] = __expf(h[hh*8 + d2] - mq); qs += es[d2]; }
        const float inv = __builtin_amdgcn_rcpf(qs);
        #pragma unroll
        for (int e = 0; e < 8; e++){
            float a = 0.f;
            #pragma unroll
            for (int d2 = 0; d2 < 8; d2++) a += es[d2] * kv[hh*64 + d2*8 + e];
            attn[hh*8 + e] = a * inv;
        }
    }

    // attn -> f16 A matrix in LDS: Ash[pos=tid][k]
    #pragma unroll
    for (int k2 = 0; k2 < 32; k2 += 2){
        f16x2 pr = { (f16_t)attn[k2], (f16_t)attn[k2+1] };
        *(f16x2*)&Ash[tid*AST + k2] = pr;
    }
    __syncthreads();   // weights + A visible to all

    // ---- phase 2: MFMA FCs ----
    const int wv   = tid >> 6;       // wave 0..3 -> positions [wv*64, wv*64+64)
    const int lane = tid & 63;
    const int lr   = lane & 15;      // A-row / D-col index
    const int lk   = lane >> 4;      // k-group 0..3
    const f32x4 zero = {0.f, 0.f, 0.f, 0.f};

    f16x8 a[4], bw[2];
    f32x4 d[8];

    // FC1
    #pragma unroll
    for (int mt = 0; mt < 4; mt++)
        a[mt] = *(const f16x8*)&Ash[(wv*64 + mt*16 + lr)*AST + lk*8];
    #pragma unroll
    for (int nt = 0; nt < 2; nt++)
        bw[nt] = *(const f16x8*)&Bsh1[(nt*16 + lr)*AST + lk*8];
    #pragma unroll
    for (int nt = 0; nt < 2; nt++)
        #pragma unroll
        for (int mt = 0; mt < 4; mt++)
            d[nt*4+mt] = __builtin_amdgcn_mfma_f32_16x16x32_f16(a[mt], bw[nt], zero, 0, 0, 0);

    // bias + gelu + write back as A2 (in-place over Ash; rows are wave-private)
    #pragma unroll
    for (int nt = 0; nt < 2; nt++){
        const float bias = sb1[nt*16 + lr];
        #pragma unroll
        for (int mt = 0; mt < 4; mt++){
            #pragma unroll
            for (int r = 0; r < 4; r++){
                const float v = gelu_f(d[nt*4+mt][r] + bias);
                Ash[(wv*64 + mt*16 + lk*4 + r)*AST + (nt*16 + lr)] = (f16_t)v;
            }
        }
    }
    __syncthreads();

    // FC2
    #pragma unroll
    for (int mt = 0; mt < 4; mt++)
        a[mt] = *(const f16x8*)&Ash[(wv*64 + mt*16 + lr)*AST + lk*8];
    #pragma unroll
    for (int nt = 0; nt < 2; nt++)
        bw[nt] = *(const f16x8*)&Bsh2[(nt*16 + lr)*AST + lk*8];
    #pragma unroll
    for (int nt = 0; nt < 2; nt++)
        #pragma unroll
        for (int mt = 0; mt < 4; mt++)
            d[nt*4+mt] = __builtin_amdgcn_mfma_f32_16x16x32_f16(a[mt], bw[nt], zero, 0, 0, 0);

    // bias + gelu on D (fp32)
    #pragma unroll
    for (int nt = 0; nt < 2; nt++){
        const float bias = sb2[nt*16 + lr];
        #pragma unroll
        for (int mt = 0; mt < 4; mt++)
            #pragma unroll
            for (int r = 0; r < 4; r++)
                d[nt*4+mt][r] = gelu_f(d[nt*4+mt][r] + bias);
    }

    if (!LAST){
        // transpose D -> [chan][pos] via LDS, 16 channels per half, coalesced stores
        #pragma unroll
        for (int nt = 0; nt < 2; nt++){
            __syncthreads();
            #pragma unroll
            for (int mt = 0; mt < 4; mt++)
                *(f32x4*)&O16[lr*OST + wv*64 + mt*16 + lk*4] = d[nt*4+mt];
            __syncthreads();
            #pragma unroll
            for (int c = 0; c < 16; c++)
                hout[base + (size_t)(nt*16 + c)*L_ + l0 + tid] = O16[c*OST + tid];
        }
    } else {
        // pooled += sum over this WG's 256 positions
        __syncthreads();   // pool[] initialized
        #pragma unroll
        for (int nt = 0; nt < 2; nt++){
            float ps = 0.f;
            #pragma unroll
            for (int mt = 0; mt < 4; mt++)
                ps += d[nt*4+mt][0] + d[nt*4+mt][1] + d[nt*4+mt][2] + d[nt*4+mt][3];
            atomicAdd(&pool[nt*16 + lr], ps);
        }
        __syncthreads();
        if (tid < 32) atomicAdd(&pooled[b*32 + tid], pool[tid]);
    }
}

// ---- head: pooled/L -> Wh+bh -> BN(eval) -> gelu -> Wf+bf ----
__global__ __launch_bounds__(1024) void head_kernel(const float* __restrict__ pooled,
                                                    const float* __restrict__ Wh,
                                                    const float* __restrict__ bh,
                                                    const float* __restrict__ gam,
                                                    const float* __restrict__ bet,
                                                    const float* __restrict__ mean,
                                                    const float* __restrict__ var,
                                                    const float* __restrict__ Wf,
                                                    const float* __restrict__ bf,
                                                    float* __restrict__ out){
    __shared__ float y2[32][32];
    const int t = threadIdx.x;      // 0..1023
    const int b = t >> 5, c = t & 31;
    float a = bh[c];
    const float invL = 1.0f / (float)L_;
    #pragma unroll
    for (int d = 0; d < 32; d++) a += (pooled[b*32 + d] * invL) * Wh[d*32 + c];
    a = (a - mean[c]) * rsqrtf(var[c] + 1e-5f) * gam[c] + bet[c];
    y2[b][c] = gelu_f(a);
    __syncthreads();
    if (t < B_*DOUT_){
        const int b2 = t / DOUT_, j = t % DOUT_;
        float r = bf[j];
        #pragma unroll
        for (int c2 = 0; c2 < 32; c2++) r += y2[b2][c2] * Wf[c2*DOUT_ + j];
        out[t] = r;
    }
}

extern "C" void kernel_launch(void* const* d_in, const int* in_sizes, int n_in,
                              void* d_out, int out_size, void* d_ws, size_t ws_size,
                              hipStream_t stream){
    (void)in_sizes; (void)n_in; (void)out_size; (void)ws_size;
    const float* x    = (const float*)d_in[0];
    const float* fW1  = (const float*)d_in[1];
    const float* fb1  = (const float*)d_in[2];
    const float* fW2  = (const float*)d_in[3];
    const float* fb2  = (const float*)d_in[4];
    const float* Wh   = (const float*)d_in[5];
    const float* bh   = (const float*)d_in[6];
    const float* gam  = (const float*)d_in[7];
    const float* bet  = (const float*)d_in[8];
    const float* mean = (const float*)d_in[9];
    const float* var  = (const float*)d_in[10];
    const float* Wf   = (const float*)d_in[11];
    const float* bf   = (const float*)d_in[12];
    float* out = (float*)d_out;

    float* hbuf   = (float*)d_ws;                          // B*C*L floats (64 MB)
    float* part   = hbuf + (size_t)B_*C_*L_;               // B*H*S*80 (~1.3 MB)
    float* kvn    = part + (size_t)B_*H_*S_*80;            // B*H*64
    float* pooled = kvn  + (size_t)B_*H_*64;               // B*C

    hipMemsetAsync(pooled, 0, B_*C_*sizeof(float), stream);

    dim3 sgrid(S_, H_, B_);
    dim3 bgrid(L_/TILE, B_);

    // block 0 (input = x, output -> hbuf)
    stats_kernel<<<sgrid, 256, 0, stream>>>(x, part);
    merge_kernel<<<B_*H_, 64, 0, stream>>>(part, kvn);
    block_kernel<false><<<bgrid, 256, 0, stream>>>(x, hbuf, kvn, fW1, fb1, fW2, fb2, nullptr);
    // block 1 (in-place on hbuf)
    stats_kernel<<<sgrid, 256, 0, stream>>>(hbuf, part);
    merge_kernel<<<B_*H_, 64, 0, stream>>>(part, kvn);
    block_kernel<false><<<bgrid, 256, 0, stream>>>(hbuf, hbuf, kvn,
        fW1 + C_*C_, fb1 + C_, fW2 + C_*C_, fb2 + C_, nullptr);
    // block 2 (no h write; reduce into pooled)
    stats_kernel<<<sgrid, 256, 0, stream>>>(hbuf, part);
    merge_kernel<<<B_*H_, 64, 0, stream>>>(part, kvn);
    block_kernel<true><<<bgrid, 256, 0, stream>>>(hbuf, nullptr, kvn,
        fW1 + 2*C_*C_, fb1 + 2*C_, fW2 + 2*C_*C_, fb2 + 2*C_, pooled);

    head_kernel<<<1, 1024, 0, stream>>>(pooled, Wh, bh, gam, bet, mean, var, Wf, bf, out);
}